// Round 1
// baseline (382.832 us; speedup 1.0000x reference)
//
#include <hip/hip_runtime.h>
#include <math.h>

#define HID 4096
#define B 32
#define H 32
#define D 128
#define KBLK 16
#define MAXB 64
#define S_MAX 1024

// out[b][n] = sum_k x[b][k] * W[n][k]
// grid.x = nmat*512; block=256. 8 cols per block; wave w handles batches 8w..8w+7.
__global__ __launch_bounds__(256) void gemv_kernel(
    const float* __restrict__ W0, const float* __restrict__ W1, const float* __restrict__ W2,
    const float* __restrict__ x, float* __restrict__ out)
{
    __shared__ float wt[8][256];
    const int bid = blockIdx.x;
    const int mat = bid >> 9;            // 512 blocks per matrix
    const int n0 = (bid & 511) << 3;     // 8 cols per block
    const float* W = (mat == 0) ? W0 : ((mat == 1) ? W1 : W2);
    float* outp = out + (size_t)mat * (B * HID);

    const int tid = threadIdx.x;
    const int lane = tid & 63;
    const int wid = tid >> 6;
    const int b0 = wid << 3;

    float acc[8][8];
#pragma unroll
    for (int c = 0; c < 8; ++c)
#pragma unroll
        for (int j = 0; j < 8; ++j) acc[c][j] = 0.f;

    for (int k0 = 0; k0 < HID; k0 += 256) {
        __syncthreads();   // protect previous tile reads
#pragma unroll
        for (int i = 0; i < 2; ++i) {
            int idx = tid + i * 256;         // 0..511
            int row = idx >> 6;              // 0..7
            int c4 = idx & 63;               // float4 index in row
            float4 v = *reinterpret_cast<const float4*>(
                &W[(size_t)(n0 + row) * HID + k0 + (c4 << 2)]);
            *reinterpret_cast<float4*>(&wt[row][c4 << 2]) = v;
        }
        __syncthreads();

        float4 hs4[8];
#pragma unroll
        for (int j = 0; j < 8; ++j)
            hs4[j] = *reinterpret_cast<const float4*>(
                &x[(size_t)(b0 + j) * HID + k0 + (lane << 2)]);

#pragma unroll
        for (int c = 0; c < 8; ++c) {
            float4 w4 = *reinterpret_cast<const float4*>(&wt[c][lane << 2]);
#pragma unroll
            for (int j = 0; j < 8; ++j) {
                acc[c][j] += w4.x * hs4[j].x;
                acc[c][j] += w4.y * hs4[j].y;
                acc[c][j] += w4.z * hs4[j].z;
                acc[c][j] += w4.w * hs4[j].w;
            }
        }
    }

    // butterfly reduce each acc over the 64 lanes
#pragma unroll
    for (int m = 1; m < 64; m <<= 1) {
#pragma unroll
        for (int c = 0; c < 8; ++c)
#pragma unroll
            for (int j = 0; j < 8; ++j)
                acc[c][j] += __shfl_xor(acc[c][j], m, 64);
    }
    // lane (c*8+j) writes acc[c][j]; static-index select chain (no scratch)
    float myval = 0.f;
#pragma unroll
    for (int c = 0; c < 8; ++c)
#pragma unroll
        for (int j = 0; j < 8; ++j)
            myval = (lane == (c * 8 + j)) ? acc[c][j] : myval;
    const int oc = lane >> 3;
    const int oj = lane & 7;
    outp[(size_t)(b0 + oj) * HID + n0 + oc] = myval;
}

// RoPE in-place on q (mat 0) and k (mat 1) in qkv ws. grid = B*H blocks, 64 threads.
__global__ __launch_bounds__(64) void rope_kernel(float* __restrict__ qkv,
                                                  const int* __restrict__ positions)
{
    const int bh = blockIdx.x;
    const int b = bh >> 5;
    const int h = bh & 31;
    const int d = threadIdx.x;  // 0..63 pair index
    const float pos = (float)positions[b];
    // inv_freq = 10000^(-d/64) = 2^(-d * log2(10000)/64)
    const float inv = exp2f(-(float)d * 0.20762050593046013f);
    const float f = pos * inv;
    const float cs = cosf(f);
    const float sn = sinf(f);
#pragma unroll
    for (int mat = 0; mat < 2; ++mat) {
        float* base = qkv + (size_t)mat * (B * HID) + (size_t)b * HID + h * D;
        float x1 = base[d];
        float x2 = base[d + 64];
        base[d] = x1 * cs - x2 * sn;
        base[d + 64] = x1 * sn + x2 * cs;
    }
}

// Paged attention decode. grid = (H, B), block = 256.
__global__ __launch_bounds__(256) void attn_kernel(
    const float* __restrict__ qkv,       // [3][B][HID]
    const float* __restrict__ k_cache,   // [NBLK*KBLK][H][D]
    const float* __restrict__ v_cache,
    const int* __restrict__ block_tables, // [B][MAXB]
    const int* __restrict__ context_lens,
    const int* __restrict__ positions,
    float* __restrict__ attn_out)        // [B][HID]
{
    const int h = blockIdx.x;
    const int b = blockIdx.y;
    const int tid = threadIdx.x;
    const int L = context_lens[b];
    const int pos = positions[b];

    __shared__ float qs[D];
    __shared__ float sc[S_MAX];
    __shared__ float red[8];
    __shared__ int btl[MAXB];
    __shared__ float outred[D];

    const float* qptr = qkv + (size_t)b * HID + h * D;
    if (tid < D) qs[tid] = qptr[tid];
    if (tid < MAXB) btl[tid] = block_tables[b * MAXB + tid];
    __syncthreads();

    const float* knew = qkv + (size_t)(B * HID) + (size_t)b * HID + h * D;
    const float* vnew = qkv + (size_t)(2 * B * HID) + (size_t)b * HID + h * D;
    const float scale = 0.088388347648318447f; // 1/sqrt(128)

    // phase 1: scores
    for (int s = tid; s < L; s += 256) {
        const float* kp;
        if (s == pos) {
            kp = knew;
        } else {
            int slot = btl[s >> 4] * KBLK + (s & 15);
            kp = k_cache + ((size_t)slot * H + h) * D;
        }
        float sum = 0.f;
#pragma unroll
        for (int d4 = 0; d4 < D; d4 += 4) {
            float4 kv = *reinterpret_cast<const float4*>(kp + d4);
            float4 qv = *reinterpret_cast<const float4*>(&qs[d4]);
            sum += qv.x * kv.x + qv.y * kv.y + qv.z * kv.z + qv.w * kv.w;
        }
        sc[s] = sum * scale;
    }

    // phase 2: softmax (unnormalized p; divide at the end)
    float lmax = -1e30f;
    for (int s = tid; s < L; s += 256) lmax = fmaxf(lmax, sc[s]);
#pragma unroll
    for (int m = 32; m; m >>= 1) lmax = fmaxf(lmax, __shfl_xor(lmax, m, 64));
    if ((tid & 63) == 0) red[tid >> 6] = lmax;
    __syncthreads();
    const float gmax = fmaxf(fmaxf(red[0], red[1]), fmaxf(red[2], red[3]));

    float lsum = 0.f;
    for (int s = tid; s < L; s += 256) {
        float p = __expf(sc[s] - gmax);
        sc[s] = p;
        lsum += p;
    }
#pragma unroll
    for (int m = 32; m; m >>= 1) lsum += __shfl_xor(lsum, m, 64);
    if ((tid & 63) == 0) red[4 + (tid >> 6)] = lsum;
    __syncthreads();   // sc fully written + red[4..7] visible
    const float gsum = red[4] + red[5] + red[6] + red[7];
    const float inv = 1.f / gsum;

    // phase 3: O = P·V ; 2 s-groups × 128 d-threads
    const int d = tid & 127;
    const int g = tid >> 7;
    float acc = 0.f;
    int s = g;
    for (; s + 6 < L; s += 8) {
        int s0 = s, s1 = s + 2, s2 = s + 4, s3 = s + 6;
        const float* p0 = (s0 == pos) ? vnew : v_cache + ((size_t)(btl[s0 >> 4] * KBLK + (s0 & 15)) * H + h) * D;
        const float* p1 = (s1 == pos) ? vnew : v_cache + ((size_t)(btl[s1 >> 4] * KBLK + (s1 & 15)) * H + h) * D;
        const float* p2 = (s2 == pos) ? vnew : v_cache + ((size_t)(btl[s2 >> 4] * KBLK + (s2 & 15)) * H + h) * D;
        const float* p3 = (s3 == pos) ? vnew : v_cache + ((size_t)(btl[s3 >> 4] * KBLK + (s3 & 15)) * H + h) * D;
        float a0 = p0[d], a1 = p1[d], a2 = p2[d], a3 = p3[d];
        acc += sc[s0] * a0;
        acc += sc[s1] * a1;
        acc += sc[s2] * a2;
        acc += sc[s3] * a3;
    }
    for (; s < L; s += 2) {
        const float* vp = (s == pos) ? vnew : v_cache + ((size_t)(btl[s >> 4] * KBLK + (s & 15)) * H + h) * D;
        acc += sc[s] * vp[d];
    }
    if (g == 1) outred[d] = acc;
    __syncthreads();
    if (g == 0) attn_out[(size_t)b * HID + h * D + d] = (acc + outred[d]) * inv;
}

extern "C" void kernel_launch(void* const* d_in, const int* in_sizes, int n_in,
                              void* d_out, int out_size, void* d_ws, size_t ws_size,
                              hipStream_t stream) {
    const float* hs        = (const float*)d_in[0];
    const float* k_cache   = (const float*)d_in[1];
    const float* v_cache   = (const float*)d_in[2];
    const float* Wq        = (const float*)d_in[3];
    const float* Wk        = (const float*)d_in[4];
    const float* Wv        = (const float*)d_in[5];
    const float* Wo        = (const float*)d_in[6];
    const int*   positions = (const int*)d_in[7];
    const int*   block_tables = (const int*)d_in[9];
    const int*   context_lens = (const int*)d_in[10];
    float* out = (float*)d_out;

    float* qkv = (float*)d_ws;                        // [3][B][HID]
    float* attn_ws = qkv + (size_t)3 * B * HID;       // [B][HID]

    gemv_kernel<<<dim3(3 * 512), 256, 0, stream>>>(Wq, Wk, Wv, hs, qkv);
    rope_kernel<<<dim3(B * H), 64, 0, stream>>>(qkv, positions);
    attn_kernel<<<dim3(H, B), 256, 0, stream>>>(qkv, k_cache, v_cache,
                                                block_tables, context_lens, positions, attn_ws);
    gemv_kernel<<<dim3(512), 256, 0, stream>>>(Wo, Wo, Wo, attn_ws, out);
}

// Round 2
// 288.295 us; speedup vs baseline: 1.3279x; 1.3279x over previous
//
#include <hip/hip_runtime.h>
#include <math.h>

#define HID 4096
#define B 32
#define H 32
#define D 128
#define KBLK 16
#define MAXB 64
#define S_MAX 1024

// out[b][n] = sum_k x[b][k] * W[n][k]
// grid.x = nmat*512; block=256. 8 cols per block; wave w handles batches 8w..8w+7.
__global__ __launch_bounds__(256) void gemv_kernel(
    const float* __restrict__ W0, const float* __restrict__ W1, const float* __restrict__ W2,
    const float* __restrict__ x, float* __restrict__ out)
{
    __shared__ float wt[8][256];
    const int bid = blockIdx.x;
    const int mat = bid >> 9;            // 512 blocks per matrix
    const int n0 = (bid & 511) << 3;     // 8 cols per block
    const float* W = (mat == 0) ? W0 : ((mat == 1) ? W1 : W2);
    float* outp = out + (size_t)mat * (B * HID);

    const int tid = threadIdx.x;
    const int lane = tid & 63;
    const int wid = tid >> 6;
    const int b0 = wid << 3;

    float acc[8][8];
#pragma unroll
    for (int c = 0; c < 8; ++c)
#pragma unroll
        for (int j = 0; j < 8; ++j) acc[c][j] = 0.f;

    for (int k0 = 0; k0 < HID; k0 += 256) {
        __syncthreads();   // protect previous tile reads
#pragma unroll
        for (int i = 0; i < 2; ++i) {
            int idx = tid + i * 256;         // 0..511
            int row = idx >> 6;              // 0..7
            int c4 = idx & 63;               // float4 index in row
            float4 v = *reinterpret_cast<const float4*>(
                &W[(size_t)(n0 + row) * HID + k0 + (c4 << 2)]);
            *reinterpret_cast<float4*>(&wt[row][c4 << 2]) = v;
        }
        __syncthreads();

        float4 hs4[8];
#pragma unroll
        for (int j = 0; j < 8; ++j)
            hs4[j] = *reinterpret_cast<const float4*>(
                &x[(size_t)(b0 + j) * HID + k0 + (lane << 2)]);

#pragma unroll
        for (int c = 0; c < 8; ++c) {
            float4 w4 = *reinterpret_cast<const float4*>(&wt[c][lane << 2]);
#pragma unroll
            for (int j = 0; j < 8; ++j) {
                acc[c][j] += w4.x * hs4[j].x;
                acc[c][j] += w4.y * hs4[j].y;
                acc[c][j] += w4.z * hs4[j].z;
                acc[c][j] += w4.w * hs4[j].w;
            }
        }
    }

    // butterfly reduce each acc over the 64 lanes
#pragma unroll
    for (int m = 1; m < 64; m <<= 1) {
#pragma unroll
        for (int c = 0; c < 8; ++c)
#pragma unroll
            for (int j = 0; j < 8; ++j)
                acc[c][j] += __shfl_xor(acc[c][j], m, 64);
    }
    // lane (c*8+j) writes acc[c][j]; static-index select chain (no scratch)
    float myval = 0.f;
#pragma unroll
    for (int c = 0; c < 8; ++c)
#pragma unroll
        for (int j = 0; j < 8; ++j)
            myval = (lane == (c * 8 + j)) ? acc[c][j] : myval;
    const int oc = lane >> 3;
    const int oj = lane & 7;
    outp[(size_t)(b0 + oj) * HID + n0 + oc] = myval;
}

// RoPE in-place on q (mat 0) and k (mat 1) in qkv ws. grid = B*H blocks, 64 threads.
__global__ __launch_bounds__(64) void rope_kernel(float* __restrict__ qkv,
                                                  const int* __restrict__ positions)
{
    const int bh = blockIdx.x;
    const int b = bh >> 5;
    const int h = bh & 31;
    const int d = threadIdx.x;  // 0..63 pair index
    const float pos = (float)positions[b];
    // inv_freq = 10000^(-d/64) = 2^(-d * log2(10000)/64)
    const float inv = exp2f(-(float)d * 0.20762050593046013f);
    const float f = pos * inv;
    const float cs = cosf(f);
    const float sn = sinf(f);
#pragma unroll
    for (int mat = 0; mat < 2; ++mat) {
        float* base = qkv + (size_t)mat * (B * HID) + (size_t)b * HID + h * D;
        float x1 = base[d];
        float x2 = base[d + 64];
        base[d] = x1 * cs - x2 * sn;
        base[d + 64] = x1 * sn + x2 * cs;
    }
}

// Paged attention decode. grid = (H, B), block = 256.
// Phase 1: one s per HALF-WAVE (32 lanes x float4 = 512B coalesced per load).
// Phase 3: one s per WAVE (64 lanes x float2 = 512B coalesced per load).
__global__ __launch_bounds__(256) void attn_kernel(
    const float* __restrict__ qkv,       // [3][B][HID]
    const float* __restrict__ k_cache,   // [NBLK*KBLK][H][D]
    const float* __restrict__ v_cache,
    const int* __restrict__ block_tables, // [B][MAXB]
    const int* __restrict__ context_lens,
    const int* __restrict__ positions,
    float* __restrict__ attn_out)        // [B][HID]
{
    const int h = blockIdx.x;
    const int b = blockIdx.y;
    const int tid = threadIdx.x;
    const int L = context_lens[b];
    const int pos = positions[b];

    __shared__ float sc[S_MAX];
    __shared__ float red[8];
    __shared__ int btl[MAXB];
    __shared__ float o4[4][D];

    if (tid < MAXB) btl[tid] = block_tables[b * MAXB + tid];
    __syncthreads();

    const float* qptr = qkv + (size_t)b * HID + h * D;
    const float* knew = qkv + (size_t)(B * HID) + (size_t)b * HID + h * D;
    const float* vnew = qkv + (size_t)(2 * B * HID) + (size_t)b * HID + h * D;
    const float scale = 0.088388347648318447f; // 1/sqrt(128)

    // ---- phase 1: scores ----
    const int hw = tid >> 5;   // half-wave id 0..7
    const int hl = tid & 31;   // lane within half-wave
    const float4 qv = *reinterpret_cast<const float4*>(qptr + (hl << 2));

    int s = hw;
    for (; s + 8 < L; s += 16) {
        const int s1 = s + 8;
        const float* kp0 = (s == pos) ? knew
            : k_cache + ((size_t)(btl[s >> 4] * KBLK + (s & 15)) * H + h) * D;
        const float* kp1 = (s1 == pos) ? knew
            : k_cache + ((size_t)(btl[s1 >> 4] * KBLK + (s1 & 15)) * H + h) * D;
        float4 k0 = *reinterpret_cast<const float4*>(kp0 + (hl << 2));
        float4 k1 = *reinterpret_cast<const float4*>(kp1 + (hl << 2));
        float d0 = qv.x * k0.x + qv.y * k0.y + qv.z * k0.z + qv.w * k0.w;
        float d1 = qv.x * k1.x + qv.y * k1.y + qv.z * k1.z + qv.w * k1.w;
#pragma unroll
        for (int m = 16; m; m >>= 1) {
            d0 += __shfl_xor(d0, m, 64);
            d1 += __shfl_xor(d1, m, 64);
        }
        if (hl == 0) { sc[s] = d0 * scale; sc[s1] = d1 * scale; }
    }
    for (; s < L; s += 8) {
        const float* kp = (s == pos) ? knew
            : k_cache + ((size_t)(btl[s >> 4] * KBLK + (s & 15)) * H + h) * D;
        float4 k0 = *reinterpret_cast<const float4*>(kp + (hl << 2));
        float d0 = qv.x * k0.x + qv.y * k0.y + qv.z * k0.z + qv.w * k0.w;
#pragma unroll
        for (int m = 16; m; m >>= 1) d0 += __shfl_xor(d0, m, 64);
        if (hl == 0) sc[s] = d0 * scale;
    }
    __syncthreads();  // sc visible to all threads

    // ---- phase 2: softmax (unnormalized; divide in epilogue) ----
    float lmax = -1e30f;
    for (int i = tid; i < L; i += 256) lmax = fmaxf(lmax, sc[i]);
#pragma unroll
    for (int m = 32; m; m >>= 1) lmax = fmaxf(lmax, __shfl_xor(lmax, m, 64));
    if ((tid & 63) == 0) red[tid >> 6] = lmax;
    __syncthreads();
    const float gmax = fmaxf(fmaxf(red[0], red[1]), fmaxf(red[2], red[3]));

    float lsum = 0.f;
    for (int i = tid; i < L; i += 256) {
        float p = __expf(sc[i] - gmax);
        sc[i] = p;
        lsum += p;
    }
#pragma unroll
    for (int m = 32; m; m >>= 1) lsum += __shfl_xor(lsum, m, 64);
    if ((tid & 63) == 0) red[4 + (tid >> 6)] = lsum;
    __syncthreads();   // sc fully written + red[4..7] visible
    const float inv = 1.f / (red[4] + red[5] + red[6] + red[7]);

    // ---- phase 3: O = P.V ----
    const int w = tid >> 6;          // wave 0..3
    const int l2 = (tid & 63) << 1;  // float2 offset in d
    float accx = 0.f, accy = 0.f;
    s = w;
    for (; s + 4 < L; s += 8) {
        const int s1 = s + 4;
        const float* vp0 = (s == pos) ? vnew
            : v_cache + ((size_t)(btl[s >> 4] * KBLK + (s & 15)) * H + h) * D;
        const float* vp1 = (s1 == pos) ? vnew
            : v_cache + ((size_t)(btl[s1 >> 4] * KBLK + (s1 & 15)) * H + h) * D;
        float2 v0 = *reinterpret_cast<const float2*>(vp0 + l2);
        float2 v1 = *reinterpret_cast<const float2*>(vp1 + l2);
        float p0 = sc[s], p1 = sc[s1];
        accx += p0 * v0.x; accy += p0 * v0.y;
        accx += p1 * v1.x; accy += p1 * v1.y;
    }
    for (; s < L; s += 4) {
        const float* vp = (s == pos) ? vnew
            : v_cache + ((size_t)(btl[s >> 4] * KBLK + (s & 15)) * H + h) * D;
        float2 v0 = *reinterpret_cast<const float2*>(vp + l2);
        float p0 = sc[s];
        accx += p0 * v0.x; accy += p0 * v0.y;
    }
    o4[w][l2] = accx;
    o4[w][l2 + 1] = accy;
    __syncthreads();
    if (tid < D) {
        float o = (o4[0][tid] + o4[1][tid] + o4[2][tid] + o4[3][tid]) * inv;
        attn_out[(size_t)b * HID + h * D + tid] = o;
    }
}

extern "C" void kernel_launch(void* const* d_in, const int* in_sizes, int n_in,
                              void* d_out, int out_size, void* d_ws, size_t ws_size,
                              hipStream_t stream) {
    const float* hs        = (const float*)d_in[0];
    const float* k_cache   = (const float*)d_in[1];
    const float* v_cache   = (const float*)d_in[2];
    const float* Wq        = (const float*)d_in[3];
    const float* Wk        = (const float*)d_in[4];
    const float* Wv        = (const float*)d_in[5];
    const float* Wo        = (const float*)d_in[6];
    const int*   positions = (const int*)d_in[7];
    const int*   block_tables = (const int*)d_in[9];
    const int*   context_lens = (const int*)d_in[10];
    float* out = (float*)d_out;

    float* qkv = (float*)d_ws;                        // [3][B][HID]
    float* attn_ws = qkv + (size_t)3 * B * HID;       // [B][HID]

    gemv_kernel<<<dim3(3 * 512), 256, 0, stream>>>(Wq, Wk, Wv, hs, qkv);
    rope_kernel<<<dim3(B * H), 64, 0, stream>>>(qkv, positions);
    attn_kernel<<<dim3(H, B), 256, 0, stream>>>(qkv, k_cache, v_cache,
                                                block_tables, context_lens, positions, attn_ws);
    gemv_kernel<<<dim3(512), 256, 0, stream>>>(Wo, Wo, Wo, attn_ws, out);
}

// Round 3
// 267.271 us; speedup vs baseline: 1.4324x; 1.0787x over previous
//
#include <hip/hip_runtime.h>
#include <math.h>

#define HID 4096
#define B 32
#define H 32
#define D 128
#define KBLK 16
#define MAXB 64
#define S_MAX 1024
#define CHUNK 256
#define NCHUNK 4

// out[b][n] = sum_k x[b][k] * W[n][k]
// grid.x = nmat*512; block=256. 8 cols per block; wave w handles batches 8w..8w+7.
__global__ __launch_bounds__(256) void gemv_kernel(
    const float* __restrict__ W0, const float* __restrict__ W1, const float* __restrict__ W2,
    const float* __restrict__ x, float* __restrict__ out)
{
    __shared__ float wt[8][256];
    const int bid = blockIdx.x;
    const int mat = bid >> 9;            // 512 blocks per matrix
    const int n0 = (bid & 511) << 3;     // 8 cols per block
    const float* W = (mat == 0) ? W0 : ((mat == 1) ? W1 : W2);
    float* outp = out + (size_t)mat * (B * HID);

    const int tid = threadIdx.x;
    const int lane = tid & 63;
    const int wid = tid >> 6;
    const int b0 = wid << 3;

    float acc[8][8];
#pragma unroll
    for (int c = 0; c < 8; ++c)
#pragma unroll
        for (int j = 0; j < 8; ++j) acc[c][j] = 0.f;

    for (int k0 = 0; k0 < HID; k0 += 256) {
        __syncthreads();   // protect previous tile reads
#pragma unroll
        for (int i = 0; i < 2; ++i) {
            int idx = tid + i * 256;         // 0..511
            int row = idx >> 6;              // 0..7
            int c4 = idx & 63;               // float4 index in row
            float4 v = *reinterpret_cast<const float4*>(
                &W[(size_t)(n0 + row) * HID + k0 + (c4 << 2)]);
            *reinterpret_cast<float4*>(&wt[row][c4 << 2]) = v;
        }
        __syncthreads();

        float4 hs4[8];
#pragma unroll
        for (int j = 0; j < 8; ++j)
            hs4[j] = *reinterpret_cast<const float4*>(
                &x[(size_t)(b0 + j) * HID + k0 + (lane << 2)]);

#pragma unroll
        for (int c = 0; c < 8; ++c) {
            float4 w4 = *reinterpret_cast<const float4*>(&wt[c][lane << 2]);
#pragma unroll
            for (int j = 0; j < 8; ++j) {
                acc[c][j] += w4.x * hs4[j].x;
                acc[c][j] += w4.y * hs4[j].y;
                acc[c][j] += w4.z * hs4[j].z;
                acc[c][j] += w4.w * hs4[j].w;
            }
        }
    }

    // butterfly reduce each acc over the 64 lanes
#pragma unroll
    for (int m = 1; m < 64; m <<= 1) {
#pragma unroll
        for (int c = 0; c < 8; ++c)
#pragma unroll
            for (int j = 0; j < 8; ++j)
                acc[c][j] += __shfl_xor(acc[c][j], m, 64);
    }
    // lane (c*8+j) writes acc[c][j]; static-index select chain (no scratch)
    float myval = 0.f;
#pragma unroll
    for (int c = 0; c < 8; ++c)
#pragma unroll
        for (int j = 0; j < 8; ++j)
            myval = (lane == (c * 8 + j)) ? acc[c][j] : myval;
    const int oc = lane >> 3;
    const int oj = lane & 7;
    outp[(size_t)(b0 + oj) * HID + n0 + oc] = myval;
}

// RoPE in-place on q (mat 0) and k (mat 1) in qkv ws. grid = B*H blocks, 64 threads.
__global__ __launch_bounds__(64) void rope_kernel(float* __restrict__ qkv,
                                                  const int* __restrict__ positions)
{
    const int bh = blockIdx.x;
    const int b = bh >> 5;
    const int h = bh & 31;
    const int d = threadIdx.x;  // 0..63 pair index
    const float pos = (float)positions[b];
    const float inv = exp2f(-(float)d * 0.20762050593046013f); // 10000^(-d/64)
    const float f = pos * inv;
    const float cs = cosf(f);
    const float sn = sinf(f);
#pragma unroll
    for (int mat = 0; mat < 2; ++mat) {
        float* base = qkv + (size_t)mat * (B * HID) + (size_t)b * HID + h * D;
        float x1 = base[d];
        float x2 = base[d + 64];
        base[d] = x1 * cs - x2 * sn;
        base[d + 64] = x1 * sn + x2 * cs;
    }
}

// Flash-decode partial: grid (H, NCHUNK, B), block = 256.
// Chunk c covers slots [c*256, min((c+1)*256, L)). Emits m_c, l_c, o_c[D]
// (o_c unnormalized: sum of exp(score - m_c) * v).
__global__ __launch_bounds__(256) void attn_partial_kernel(
    const float* __restrict__ qkv,       // [3][B][HID]
    const float* __restrict__ k_cache,   // [NBLK*KBLK][H][D]
    const float* __restrict__ v_cache,
    const int* __restrict__ block_tables, // [B][MAXB]
    const int* __restrict__ context_lens,
    const int* __restrict__ positions,
    float* __restrict__ pm,              // [B*H][NCHUNK]
    float* __restrict__ pl,              // [B*H][NCHUNK]
    float* __restrict__ po)              // [B*H][NCHUNK][D]
{
    const int h = blockIdx.x;
    const int c = blockIdx.y;
    const int b = blockIdx.z;
    const int L = context_lens[b];
    const int s0 = c << 8;
    if (s0 >= L) return;
    const int Lc = min(L - s0, CHUNK);   // valid slots in this chunk
    const int pos = positions[b];
    const int tid = threadIdx.x;

    __shared__ float sc[CHUNK];
    __shared__ float red[8];
    __shared__ int btl[16];
    __shared__ float o4[4][D];

    if (tid < 16) btl[tid] = block_tables[b * MAXB + (c << 4) + tid];
    __syncthreads();

    const float* qptr = qkv + (size_t)b * HID + h * D;
    const float* knew = qkv + (size_t)(B * HID) + (size_t)b * HID + h * D;
    const float* vnew = qkv + (size_t)(2 * B * HID) + (size_t)b * HID + h * D;
    const float scale = 0.088388347648318447f; // 1/sqrt(128)

    // ---- phase 1: scores. one s per half-wave (32 lanes x float4 = 512B) ----
    const int hw = tid >> 5;   // 0..7
    const int hl = tid & 31;
    const float4 qv = *reinterpret_cast<const float4*>(qptr + (hl << 2));

    int i = hw;
    for (; i + 8 < Lc; i += 16) {
        const int sA = s0 + i, sB = s0 + i + 8;
        const float* kp0 = (sA == pos) ? knew
            : k_cache + ((size_t)(btl[i >> 4] * KBLK + (sA & 15)) * H + h) * D;
        const float* kp1 = (sB == pos) ? knew
            : k_cache + ((size_t)(btl[(i + 8) >> 4] * KBLK + (sB & 15)) * H + h) * D;
        float4 k0 = *reinterpret_cast<const float4*>(kp0 + (hl << 2));
        float4 k1 = *reinterpret_cast<const float4*>(kp1 + (hl << 2));
        float d0 = qv.x * k0.x + qv.y * k0.y + qv.z * k0.z + qv.w * k0.w;
        float d1 = qv.x * k1.x + qv.y * k1.y + qv.z * k1.z + qv.w * k1.w;
#pragma unroll
        for (int m = 16; m; m >>= 1) {
            d0 += __shfl_xor(d0, m, 64);
            d1 += __shfl_xor(d1, m, 64);
        }
        if (hl == 0) { sc[i] = d0 * scale; sc[i + 8] = d1 * scale; }
    }
    for (; i < Lc; i += 8) {
        const int sA = s0 + i;
        const float* kp = (sA == pos) ? knew
            : k_cache + ((size_t)(btl[i >> 4] * KBLK + (sA & 15)) * H + h) * D;
        float4 k0 = *reinterpret_cast<const float4*>(kp + (hl << 2));
        float d0 = qv.x * k0.x + qv.y * k0.y + qv.z * k0.z + qv.w * k0.w;
#pragma unroll
        for (int m = 16; m; m >>= 1) d0 += __shfl_xor(d0, m, 64);
        if (hl == 0) sc[i] = d0 * scale;
    }
    for (; i < CHUNK; i += 8)
        if (hl == 0) sc[i] = -1e30f;
    __syncthreads();

    // ---- phase 2: chunk-local softmax (one element per thread) ----
    const int w = tid >> 6;
    const float x = sc[tid];
    float m = x;
#pragma unroll
    for (int mm = 32; mm; mm >>= 1) m = fmaxf(m, __shfl_xor(m, mm, 64));
    if ((tid & 63) == 0) red[w] = m;
    __syncthreads();
    const float gm = fmaxf(fmaxf(red[0], red[1]), fmaxf(red[2], red[3]));

    float p = (x > -1e29f) ? __expf(x - gm) : 0.f;
    sc[tid] = p;
    float l = p;
#pragma unroll
    for (int mm = 32; mm; mm >>= 1) l += __shfl_xor(l, mm, 64);
    if ((tid & 63) == 0) red[4 + w] = l;
    __syncthreads();   // sc[] = p visible + red[4..7]
    const float gl = red[4] + red[5] + red[6] + red[7];

    // ---- phase 3: partial O = P.V ; one s per wave (64 lanes x float2) ----
    const int l2 = (tid & 63) << 1;
    float accx = 0.f, accy = 0.f;
    i = w;
    for (; i + 4 < Lc; i += 8) {
        const int sA = s0 + i, sB = s0 + i + 4;
        const float* vp0 = (sA == pos) ? vnew
            : v_cache + ((size_t)(btl[i >> 4] * KBLK + (sA & 15)) * H + h) * D;
        const float* vp1 = (sB == pos) ? vnew
            : v_cache + ((size_t)(btl[(i + 4) >> 4] * KBLK + (sB & 15)) * H + h) * D;
        float2 v0 = *reinterpret_cast<const float2*>(vp0 + l2);
        float2 v1 = *reinterpret_cast<const float2*>(vp1 + l2);
        float p0 = sc[i], p1 = sc[i + 4];
        accx += p0 * v0.x; accy += p0 * v0.y;
        accx += p1 * v1.x; accy += p1 * v1.y;
    }
    for (; i < Lc; i += 4) {
        const float* vp = (s0 + i == pos) ? vnew
            : v_cache + ((size_t)(btl[i >> 4] * KBLK + ((s0 + i) & 15)) * H + h) * D;
        float2 v0 = *reinterpret_cast<const float2*>(vp + l2);
        float p0 = sc[i];
        accx += p0 * v0.x; accy += p0 * v0.y;
    }
    o4[w][l2] = accx;
    o4[w][l2 + 1] = accy;
    __syncthreads();

    const int bh = b * H + h;
    if (tid < D) {
        float o = o4[0][tid] + o4[1][tid] + o4[2][tid] + o4[3][tid];
        po[((size_t)bh * NCHUNK + c) * D + tid] = o;
    } else if (tid == D) {
        pm[bh * NCHUNK + c] = gm;
        pl[bh * NCHUNK + c] = gl;
    }
}

// Combine partials. grid = B*H, block = 128.
__global__ __launch_bounds__(128) void attn_combine_kernel(
    const float* __restrict__ pm, const float* __restrict__ pl,
    const float* __restrict__ po, const int* __restrict__ context_lens,
    float* __restrict__ attn_out)
{
    const int bh = blockIdx.x;
    const int b = bh >> 5;
    const int tid = threadIdx.x;
    const int nc = (context_lens[b] + CHUNK - 1) >> 8;

    float m = -1e30f;
    for (int c = 0; c < nc; ++c) m = fmaxf(m, pm[bh * NCHUNK + c]);
    float wsum = 0.f, o = 0.f;
    for (int c = 0; c < nc; ++c) {
        float wc = __expf(pm[bh * NCHUNK + c] - m);
        wsum += wc * pl[bh * NCHUNK + c];
        o += wc * po[((size_t)bh * NCHUNK + c) * D + tid];
    }
    attn_out[(size_t)bh * D + tid] = o / wsum;
}

extern "C" void kernel_launch(void* const* d_in, const int* in_sizes, int n_in,
                              void* d_out, int out_size, void* d_ws, size_t ws_size,
                              hipStream_t stream) {
    const float* hs        = (const float*)d_in[0];
    const float* k_cache   = (const float*)d_in[1];
    const float* v_cache   = (const float*)d_in[2];
    const float* Wq        = (const float*)d_in[3];
    const float* Wk        = (const float*)d_in[4];
    const float* Wv        = (const float*)d_in[5];
    const float* Wo        = (const float*)d_in[6];
    const int*   positions = (const int*)d_in[7];
    const int*   block_tables = (const int*)d_in[9];
    const int*   context_lens = (const int*)d_in[10];
    float* out = (float*)d_out;

    float* qkv     = (float*)d_ws;                         // [3][B][HID]
    float* attn_ws = qkv + (size_t)3 * B * HID;            // [B][HID]
    float* pm      = attn_ws + (size_t)B * HID;            // [B*H][NCHUNK]
    float* pl      = pm + (size_t)B * H * NCHUNK;          // [B*H][NCHUNK]
    float* po      = pl + (size_t)B * H * NCHUNK;          // [B*H][NCHUNK][D]

    gemv_kernel<<<dim3(3 * 512), 256, 0, stream>>>(Wq, Wk, Wv, hs, qkv);
    rope_kernel<<<dim3(B * H), 64, 0, stream>>>(qkv, positions);
    attn_partial_kernel<<<dim3(H, NCHUNK, B), 256, 0, stream>>>(
        qkv, k_cache, v_cache, block_tables, context_lens, positions, pm, pl, po);
    attn_combine_kernel<<<dim3(B * H), 128, 0, stream>>>(pm, pl, po, context_lens, attn_ws);
    gemv_kernel<<<dim3(512), 256, 0, stream>>>(Wo, Wo, Wo, attn_ws, out);
}

// Round 4
// 262.464 us; speedup vs baseline: 1.4586x; 1.0183x over previous
//
#include <hip/hip_runtime.h>
#include <math.h>

#define HID 4096
#define B 32
#define H 32
#define D 128
#define KBLK 16
#define MAXB 64
#define CHUNK 256
#define NCHUNK 4

// out[b][n] = sum_k x[b][k] * W[n][k]
// MODE 0: QKV (grid 3*512; mats 0,1 get fused RoPE, pair-column mapping).
// MODE 1: single matrix, no rope (grid 512).
// Block: 256 thr, 4 waves; wave w = batches 8w..8w+7; 8 cols per block.
template <int MODE>
__global__ __launch_bounds__(256) void gemv_kernel(
    const float* __restrict__ W0, const float* __restrict__ W1, const float* __restrict__ W2,
    const float* __restrict__ x, const int* __restrict__ positions, float* __restrict__ out)
{
    __shared__ float wt[8][256];
    __shared__ float buf[4][8][66];   // per-wave transpose-reduce scratch
    const int bid = blockIdx.x;
    const int mat = (MODE == 0) ? (bid >> 9) : 0;
    const int sub = bid & 511;
    const bool rope = (MODE == 0) && (mat < 2);
    const int head = sub >> 4;        // rope mapping: 16 blocks per head
    const int p0 = (sub & 15) << 2;   // pair base d = p0..p0+3
    const float* W = (mat == 0) ? W0 : ((mat == 1) ? W1 : W2);
    float* outp = out + (size_t)mat * (B * HID);

    const int tid = threadIdx.x;
    const int lane = tid & 63;
    const int wid = tid >> 6;
    const int b0 = wid << 3;

    float acc[8][8];
#pragma unroll
    for (int c = 0; c < 8; ++c)
#pragma unroll
        for (int j = 0; j < 8; ++j) acc[c][j] = 0.f;

    for (int k0 = 0; k0 < HID; k0 += 256) {
        __syncthreads();   // protect previous tile reads
#pragma unroll
        for (int i = 0; i < 2; ++i) {
            int idx = tid + (i << 8);        // 0..511
            int r = idx >> 6;                // 0..7
            int c4 = idx & 63;
            int cr = rope ? (head * 128 + p0 + (r & 3) + ((r >> 2) << 6))
                          : ((sub << 3) + r);
            float4 v = *reinterpret_cast<const float4*>(
                &W[(size_t)cr * HID + k0 + (c4 << 2)]);
            *reinterpret_cast<float4*>(&wt[r][c4 << 2]) = v;
        }
        __syncthreads();

        float4 hs4[8];
#pragma unroll
        for (int j = 0; j < 8; ++j)
            hs4[j] = *reinterpret_cast<const float4*>(
                &x[(size_t)(b0 + j) * HID + k0 + (lane << 2)]);

#pragma unroll
        for (int c = 0; c < 8; ++c) {
            float4 w4 = *reinterpret_cast<const float4*>(&wt[c][lane << 2]);
#pragma unroll
            for (int j = 0; j < 8; ++j) {
                acc[c][j] += w4.x * hs4[j].x;
                acc[c][j] += w4.y * hs4[j].y;
                acc[c][j] += w4.z * hs4[j].z;
                acc[c][j] += w4.w * hs4[j].w;
            }
        }
    }

    // ---- epilogue: per-c LDS transpose reduce (wave-private, no barrier) ----
    float res[8];
#pragma unroll
    for (int c = 0; c < 8; ++c) {
#pragma unroll
        for (int j = 0; j < 8; ++j) buf[wid][j][lane] = acc[c][j];
        __builtin_amdgcn_sched_barrier(0);
        const float* rp = &buf[wid][lane >> 3][(lane & 7) << 3];
        float4 a = *reinterpret_cast<const float4*>(rp);
        float4 bb = *reinterpret_cast<const float4*>(rp + 4);
        __builtin_amdgcn_sched_barrier(0);
        float s = ((a.x + a.y) + (a.z + a.w)) + ((bb.x + bb.y) + (bb.z + bb.w));
        s += __shfl_xor(s, 1, 64);
        s += __shfl_xor(s, 2, 64);
        s += __shfl_xor(s, 4, 64);
        res[c] = s;   // every lane: output (col c, batch j=lane>>3)
    }

    const int jme = lane >> 3;
    const int cme = lane & 7;
    float myv;
    if (rope) {
        const float pf = (float)positions[b0 + jme];
        float ro[8];
#pragma unroll
        for (int cc = 0; cc < 4; ++cc) {
            float invf = exp2f(-(float)(p0 + cc) * 0.20762050593046013f); // 10000^(-d/64)
            float f = pf * invf;
            float cs = cosf(f), sn = sinf(f);
            ro[cc]     = res[cc] * cs - res[cc + 4] * sn;
            ro[cc + 4] = res[cc] * sn + res[cc + 4] * cs;
        }
        myv = ro[0];
#pragma unroll
        for (int cc = 1; cc < 8; ++cc) myv = (cme == cc) ? ro[cc] : myv;
    } else {
        myv = res[0];
#pragma unroll
        for (int cc = 1; cc < 8; ++cc) myv = (cme == cc) ? res[cc] : myv;
    }
    const int colw = rope ? (head * 128 + p0 + (cme & 3) + ((cme >> 2) << 6))
                          : ((sub << 3) + cme);
    outp[(size_t)(b0 + jme) * HID + colw] = myv;
}

// Flash-decode partial: grid (H, NCHUNK, B), block = 256. q/k in qkv are pre-roped.
__global__ __launch_bounds__(256) void attn_partial_kernel(
    const float* __restrict__ qkv,       // [3][B][HID]
    const float* __restrict__ k_cache,   // [NBLK*KBLK][H][D]
    const float* __restrict__ v_cache,
    const int* __restrict__ block_tables, // [B][MAXB]
    const int* __restrict__ context_lens,
    const int* __restrict__ positions,
    float* __restrict__ pm,              // [B*H][NCHUNK]
    float* __restrict__ pl,              // [B*H][NCHUNK]
    float* __restrict__ po)              // [B*H][NCHUNK][D]
{
    const int h = blockIdx.x;
    const int c = blockIdx.y;
    const int b = blockIdx.z;
    const int L = context_lens[b];
    const int s0 = c << 8;
    if (s0 >= L) return;
    const int Lc = min(L - s0, CHUNK);
    const int pos = positions[b];
    const int tid = threadIdx.x;

    __shared__ float sc[CHUNK];
    __shared__ float red[8];
    __shared__ int btl[16];
    __shared__ float o4[4][D];

    if (tid < 16) btl[tid] = block_tables[b * MAXB + (c << 4) + tid];
    __syncthreads();

    const float* qptr = qkv + (size_t)b * HID + h * D;
    const float* knew = qkv + (size_t)(B * HID) + (size_t)b * HID + h * D;
    const float* vnew = qkv + (size_t)(2 * B * HID) + (size_t)b * HID + h * D;
    const float scale = 0.088388347648318447f; // 1/sqrt(128)

    // ---- phase 1: scores, one s per half-wave, 4 rows in flight ----
    const int hw = tid >> 5;
    const int hl = tid & 31;
    const float4 qv = *reinterpret_cast<const float4*>(qptr + (hl << 2));

    int i = hw;
    for (; i + 24 < Lc; i += 32) {
        const int sA = s0 + i, sB = sA + 8, sC = sA + 16, sD = sA + 24;
        const float* kp0 = (sA == pos) ? knew
            : k_cache + ((size_t)(btl[i >> 4] * KBLK + (sA & 15)) * H + h) * D;
        const float* kp1 = (sB == pos) ? knew
            : k_cache + ((size_t)(btl[(i + 8) >> 4] * KBLK + (sB & 15)) * H + h) * D;
        const float* kp2 = (sC == pos) ? knew
            : k_cache + ((size_t)(btl[(i + 16) >> 4] * KBLK + (sC & 15)) * H + h) * D;
        const float* kp3 = (sD == pos) ? knew
            : k_cache + ((size_t)(btl[(i + 24) >> 4] * KBLK + (sD & 15)) * H + h) * D;
        float4 k0 = *reinterpret_cast<const float4*>(kp0 + (hl << 2));
        float4 k1 = *reinterpret_cast<const float4*>(kp1 + (hl << 2));
        float4 k2 = *reinterpret_cast<const float4*>(kp2 + (hl << 2));
        float4 k3 = *reinterpret_cast<const float4*>(kp3 + (hl << 2));
        float d0 = qv.x * k0.x + qv.y * k0.y + qv.z * k0.z + qv.w * k0.w;
        float d1 = qv.x * k1.x + qv.y * k1.y + qv.z * k1.z + qv.w * k1.w;
        float d2 = qv.x * k2.x + qv.y * k2.y + qv.z * k2.z + qv.w * k2.w;
        float d3 = qv.x * k3.x + qv.y * k3.y + qv.z * k3.z + qv.w * k3.w;
#pragma unroll
        for (int m = 16; m; m >>= 1) {
            d0 += __shfl_xor(d0, m, 64);
            d1 += __shfl_xor(d1, m, 64);
            d2 += __shfl_xor(d2, m, 64);
            d3 += __shfl_xor(d3, m, 64);
        }
        if (hl == 0) {
            sc[i] = d0 * scale; sc[i + 8] = d1 * scale;
            sc[i + 16] = d2 * scale; sc[i + 24] = d3 * scale;
        }
    }
    for (; i < Lc; i += 8) {
        const int sA = s0 + i;
        const float* kp = (sA == pos) ? knew
            : k_cache + ((size_t)(btl[i >> 4] * KBLK + (sA & 15)) * H + h) * D;
        float4 k0 = *reinterpret_cast<const float4*>(kp + (hl << 2));
        float d0 = qv.x * k0.x + qv.y * k0.y + qv.z * k0.z + qv.w * k0.w;
#pragma unroll
        for (int m = 16; m; m >>= 1) d0 += __shfl_xor(d0, m, 64);
        if (hl == 0) sc[i] = d0 * scale;
    }
    for (; i < CHUNK; i += 8)
        if (hl == 0) sc[i] = -1e30f;
    __syncthreads();

    // ---- phase 2: chunk-local softmax (one element per thread) ----
    const int w = tid >> 6;
    const float xv = sc[tid];
    float m = xv;
#pragma unroll
    for (int mm = 32; mm; mm >>= 1) m = fmaxf(m, __shfl_xor(m, mm, 64));
    if ((tid & 63) == 0) red[w] = m;
    __syncthreads();
    const float gm = fmaxf(fmaxf(red[0], red[1]), fmaxf(red[2], red[3]));

    float p = (xv > -1e29f) ? __expf(xv - gm) : 0.f;
    sc[tid] = p;
    float l = p;
#pragma unroll
    for (int mm = 32; mm; mm >>= 1) l += __shfl_xor(l, mm, 64);
    if ((tid & 63) == 0) red[4 + w] = l;
    __syncthreads();
    const float gl = red[4] + red[5] + red[6] + red[7];

    // ---- phase 3: partial O = P.V ; one s per wave, 4 rows in flight ----
    const int l2 = (tid & 63) << 1;
    float accx = 0.f, accy = 0.f;
    i = w;
    for (; i + 12 < Lc; i += 16) {
        const int sA = s0 + i, sB = sA + 4, sC = sA + 8, sD = sA + 12;
        const float* vp0 = (sA == pos) ? vnew
            : v_cache + ((size_t)(btl[i >> 4] * KBLK + (sA & 15)) * H + h) * D;
        const float* vp1 = (sB == pos) ? vnew
            : v_cache + ((size_t)(btl[(i + 4) >> 4] * KBLK + (sB & 15)) * H + h) * D;
        const float* vp2 = (sC == pos) ? vnew
            : v_cache + ((size_t)(btl[(i + 8) >> 4] * KBLK + (sC & 15)) * H + h) * D;
        const float* vp3 = (sD == pos) ? vnew
            : v_cache + ((size_t)(btl[(i + 12) >> 4] * KBLK + (sD & 15)) * H + h) * D;
        float2 v0 = *reinterpret_cast<const float2*>(vp0 + l2);
        float2 v1 = *reinterpret_cast<const float2*>(vp1 + l2);
        float2 v2 = *reinterpret_cast<const float2*>(vp2 + l2);
        float2 v3 = *reinterpret_cast<const float2*>(vp3 + l2);
        float p0 = sc[i], p1 = sc[i + 4], p2 = sc[i + 8], p3 = sc[i + 12];
        accx += p0 * v0.x; accy += p0 * v0.y;
        accx += p1 * v1.x; accy += p1 * v1.y;
        accx += p2 * v2.x; accy += p2 * v2.y;
        accx += p3 * v3.x; accy += p3 * v3.y;
    }
    for (; i < Lc; i += 4) {
        const float* vp = (s0 + i == pos) ? vnew
            : v_cache + ((size_t)(btl[i >> 4] * KBLK + ((s0 + i) & 15)) * H + h) * D;
        float2 v0 = *reinterpret_cast<const float2*>(vp + l2);
        float p0 = sc[i];
        accx += p0 * v0.x; accy += p0 * v0.y;
    }
    o4[w][l2] = accx;
    o4[w][l2 + 1] = accy;
    __syncthreads();

    const int bh = b * H + h;
    if (tid < D) {
        float o = o4[0][tid] + o4[1][tid] + o4[2][tid] + o4[3][tid];
        po[((size_t)bh * NCHUNK + c) * D + tid] = o;
    } else if (tid == D) {
        pm[bh * NCHUNK + c] = gm;
        pl[bh * NCHUNK + c] = gl;
    }
}

// Combine partials. grid = B*H, block = 128.
__global__ __launch_bounds__(128) void attn_combine_kernel(
    const float* __restrict__ pm, const float* __restrict__ pl,
    const float* __restrict__ po, const int* __restrict__ context_lens,
    float* __restrict__ attn_out)
{
    const int bh = blockIdx.x;
    const int b = bh >> 5;
    const int tid = threadIdx.x;
    const int nc = (context_lens[b] + CHUNK - 1) >> 8;

    float m = -1e30f;
    for (int c = 0; c < nc; ++c) m = fmaxf(m, pm[bh * NCHUNK + c]);
    float wsum = 0.f, o = 0.f;
    for (int c = 0; c < nc; ++c) {
        float wc = __expf(pm[bh * NCHUNK + c] - m);
        wsum += wc * pl[bh * NCHUNK + c];
        o += wc * po[((size_t)bh * NCHUNK + c) * D + tid];
    }
    attn_out[(size_t)bh * D + tid] = o / wsum;
}

extern "C" void kernel_launch(void* const* d_in, const int* in_sizes, int n_in,
                              void* d_out, int out_size, void* d_ws, size_t ws_size,
                              hipStream_t stream) {
    const float* hs        = (const float*)d_in[0];
    const float* k_cache   = (const float*)d_in[1];
    const float* v_cache   = (const float*)d_in[2];
    const float* Wq        = (const float*)d_in[3];
    const float* Wk        = (const float*)d_in[4];
    const float* Wv        = (const float*)d_in[5];
    const float* Wo        = (const float*)d_in[6];
    const int*   positions = (const int*)d_in[7];
    const int*   block_tables = (const int*)d_in[9];
    const int*   context_lens = (const int*)d_in[10];
    float* out = (float*)d_out;

    float* qkv     = (float*)d_ws;                         // [3][B][HID] (q,k pre-roped)
    float* attn_ws = qkv + (size_t)3 * B * HID;            // [B][HID]
    float* pm      = attn_ws + (size_t)B * HID;            // [B*H][NCHUNK]
    float* pl      = pm + (size_t)B * H * NCHUNK;          // [B*H][NCHUNK]
    float* po      = pl + (size_t)B * H * NCHUNK;          // [B*H][NCHUNK][D]

    gemv_kernel<0><<<dim3(3 * 512), 256, 0, stream>>>(Wq, Wk, Wv, hs, positions, qkv);
    attn_partial_kernel<<<dim3(H, NCHUNK, B), 256, 0, stream>>>(
        qkv, k_cache, v_cache, block_tables, context_lens, positions, pm, pl, po);
    attn_combine_kernel<<<dim3(B * H), 128, 0, stream>>>(pm, pl, po, context_lens, attn_ws);
    gemv_kernel<1><<<dim3(512), 256, 0, stream>>>(Wo, Wo, Wo, attn_ws, positions, out);
}